// Round 16
// baseline (160.113 us; speedup 1.0000x reference)
//
#include <hip/hip_runtime.h>
#include <hip/hip_bf16.h>
#include <math.h>

// GateFusion via bf16 MFMA (16x16x32). PERSISTENT-GRID probe: 512 blocks
// (2/CU) stage the 40KB phase-2 weights ONCE, then each wave processes 8
// contiguous 16-row tiles in a no-unroll loop (r9/r14 body verbatim).
// Rationale: r5/8/9/11/13/14/15 pinned at ~135us / 2.7 TB/s invariant to
// occupancy, flight depth, coalescing, and instruction clustering -- the
// surviving suspect is the one-shot block lifecycle (launch + 40KB staging +
// barrier + drain per 128 rows; waves live ~20us for ~1.5us of serial work).
// Known loop pathologies (r6/r12 LICM hoist -> spill -> traffic inflation)
// are blocked by asm-laundered opaque zero offsets folded into every weight
// address (regenerated per iteration => nothing is provably loop-invariant)
// + #pragma clang loop unroll(disable) (blocks r12's unroll-spill).
// out = g * (x_d@W_d) + (1-g) * (x_c@W_c),
// g = sigmoid( relu(LN(concat@Wg1)) @ Wg2 ),  per row.
//
// d_ws: fragment-linear bf16 weights; lane l of frag holds B[k(l,j)][n],
//   n = nt*16 + (l&15),  k(l,j) = ks*32 + (j>>2)*16 + (l>>4)*4 + (j&3)
// (coalesced-load k-permutation; cancels between A and B fragments).

namespace {

typedef __attribute__((ext_vector_type(8))) short short8;
typedef __attribute__((ext_vector_type(4))) float f32x4;

constexpr int CD = 64, CC = 96, CH = 64, CF = 128;
constexpr int NFG1 = 20;   // gate-weight frags (read from L1/L2)
constexpr int NFCB = 40;   // combined-output-weight frags (staged in LDS)
constexpr int NFRAG = NFG1 + NFCB;
constexpr int WCHUNKS = NFCB * 512 * 2 / 16;  // 2560 x 16B = 40960 B

__device__ inline short bf16_of(float f) {
  __hip_bfloat16 h = __float2bfloat16(f);
  return *reinterpret_cast<short*>(&h);
}

__global__ void convert_weights(const float* __restrict__ Wd,
                                const float* __restrict__ Wc,
                                const float* __restrict__ Wg1,
                                short* __restrict__ ws) {
  const int t = blockIdx.x * 256 + threadIdx.x;
  if (t >= 64 * NFRAG) return;
  const int frag = t >> 6, l = t & 63;
  const int cidx = l & 15, kb = l >> 4;
  float v[8];
  if (frag < NFG1) {
    const int ks = frag >> 2, nt = frag & 3;
    const int n = nt * 16 + cidx;
    #pragma unroll
    for (int j = 0; j < 8; ++j) {
      const int k = ks * 32 + (j >> 2) * 16 + kb * 4 + (j & 3);
      v[j] = Wg1[k * CH + n];
    }
  } else {
    const int f2 = frag - NFG1;
    const int ks = f2 >> 3, nt = f2 & 7;
    const int n = nt * 16 + cidx;
    #pragma unroll
    for (int j = 0; j < 8; ++j) {
      const int k = ks * 32 + (j >> 2) * 16 + kb * 4 + (j & 3);
      v[j] = (k < CD) ? Wd[k * CF + n] : Wc[(k - CD) * CF + n];
    }
  }
  short8 o;
  #pragma unroll
  for (int j = 0; j < 8; ++j) o[j] = bf16_of(v[j]);
  *reinterpret_cast<short8*>(ws + frag * 512 + l * 8) = o;
}

__global__ __launch_bounds__(512)
void gate_fusion_mfma(const float* __restrict__ xd,
                      const float* __restrict__ xc,
                      const float* __restrict__ gma,
                      const float* __restrict__ bta,
                      const float* __restrict__ Wg2,
                      const short* __restrict__ wf,
                      float* __restrict__ out, int nTiles, int T) {
  __shared__ short wlds[NFCB * 512];

  const int tid  = threadIdx.x;
  const int lane = tid & 63;
  const int wv   = tid >> 6;                 // 0..7
  const int cidx = lane & 15;
  const int kb   = lane >> 4;
  const int tb   = (blockIdx.x * 8 + wv) * T;   // first tile of this wave

  // ---- stage the 40 output-weight frags (40960 B) into LDS, once
  {
    const short* wsrc = wf + NFG1 * 512;
    #pragma unroll
    for (int it = 0; it < WCHUNKS / 512; ++it) {
      const int c = tid + it * 512;
      short8 v = *reinterpret_cast<const short8*>(wsrc + (size_t)c * 8);
      *reinterpret_cast<short8*>(&wlds[c * 8]) = v;
    }
  }
  __syncthreads();   // the only barrier; waves free-run afterwards

  // per-wave constants (cache-hit loads)
  float gmv[4], btv[4], w2v[4];
  #pragma unroll
  for (int nt = 0; nt < 4; ++nt) {
    const int c = nt * 16 + cidx;
    gmv[nt] = gma[c]; btv[nt] = bta[c]; w2v[nt] = Wg2[c];
  }

  const f32x4 vzero = {0.f, 0.f, 0.f, 0.f};

  #pragma clang loop unroll(disable)
  for (int i = 0; i < T; ++i) {
    const int t = tb + i;
    if (t >= nTiles) break;          // wave-uniform
    const int r0 = t * 16;

    // opaque zero, regenerated per iteration: every weight address below
    // depends on it, so no weight load is provably loop-invariant (blocks
    // the r6/r12 LICM-hoist -> spill -> traffic-inflation pathology).
    int lz = 0;
    asm volatile("" : "+s"(lz));

    // ---- load this tile's x (coalesced 64B/4-lane segments, r14 k-map)
    f32x4 buf[5][2];
    {
      const size_t row = (size_t)(r0 + cidx);
      const float* rd = xd + row * CD + kb * 4;
      const float* rc = xc + row * CC + kb * 4;
      #pragma unroll
      for (int ks = 0; ks < 5; ++ks) {
        const float* p = (ks < 2) ? (rd + ks * 32) : (rc + (ks - 2) * 32);
        buf[ks][0] = *reinterpret_cast<const f32x4*>(p);
        buf[ks][1] = *reinterpret_cast<const f32x4*>(p + 16);
      }
    }

    // ---- convert x to bf16 A-fragments
    short8 xf[5];
    #pragma unroll
    for (int ks = 0; ks < 5; ++ks) {
      short8 f;
      #pragma unroll
      for (int j = 0; j < 4; ++j) {
        f[j]     = bf16_of(buf[ks][0][j]);
        f[4 + j] = bf16_of(buf[ks][1][j]);
      }
      xf[ks] = f;
    }

    // ---- phase 1: h = x @ Wg1  [16 x 64]  (B-frags from L1/L2, laundered)
    f32x4 acc1[4];
    #pragma unroll
    for (int nt = 0; nt < 4; ++nt) acc1[nt] = vzero;

    #pragma unroll
    for (int ks = 0; ks < 5; ++ks) {
      short8 bg[4];
      #pragma unroll
      for (int nt = 0; nt < 4; ++nt)
        bg[nt] = *reinterpret_cast<const short8*>(
            wf + (ks * 4 + nt) * 512 + lane * 8 + lz);
      #pragma unroll
      for (int nt = 0; nt < 4; ++nt)
        acc1[nt] = __builtin_amdgcn_mfma_f32_16x16x32_bf16(
            xf[ks], bg[nt], acc1[nt], 0, 0, 0);
    }

    // ---- LayerNorm + relu + dot(Wg2) + sigmoid (C-fragment layout)
    float gate[4];
    {
      float s[4], q[4];
      #pragma unroll
      for (int r = 0; r < 4; ++r) {
        s[r] = 0.f; q[r] = 0.f;
        #pragma unroll
        for (int nt = 0; nt < 4; ++nt) {
          const float c = acc1[nt][r];
          s[r] += c; q[r] += c * c;
        }
      }
      #pragma unroll
      for (int m = 1; m < 16; m <<= 1)
        #pragma unroll
        for (int r = 0; r < 4; ++r) {
          s[r] += __shfl_xor(s[r], m, 64);
          q[r] += __shfl_xor(q[r], m, 64);
        }
      float p[4];
      #pragma unroll
      for (int r = 0; r < 4; ++r) {
        const float mu  = s[r] * (1.f / CH);
        const float var = q[r] * (1.f / CH) - mu * mu;
        const float rsd = rsqrtf(var + 1e-5f);
        float pp = 0.f;
        #pragma unroll
        for (int nt = 0; nt < 4; ++nt) {
          const float h = fmaxf((acc1[nt][r] - mu) * rsd * gmv[nt] + btv[nt], 0.f);
          pp += h * w2v[nt];
        }
        p[r] = pp;
      }
      #pragma unroll
      for (int m = 1; m < 16; m <<= 1)
        #pragma unroll
        for (int r = 0; r < 4; ++r) p[r] += __shfl_xor(p[r], m, 64);
      #pragma unroll
      for (int r = 0; r < 4; ++r) gate[r] = 1.f / (1.f + expf(-p[r]));
    }

    // ---- phase 2 in 4 nt-quarter slices (LDS weights, laundered index)
    #pragma unroll
    for (int q = 0; q < 4; ++q) {
      f32x4 aD[2], aC[2];
      #pragma unroll
      for (int nt = 0; nt < 2; ++nt) { aD[nt] = vzero; aC[nt] = vzero; }

      #pragma unroll
      for (int ks = 0; ks < 5; ++ks) {
        short8 bg[2];
        #pragma unroll
        for (int nt = 0; nt < 2; ++nt)
          bg[nt] = *reinterpret_cast<const short8*>(
              &wlds[(ks * 8 + q * 2 + nt) * 512 + lane * 8 + lz]);
        if (ks < 2) {
          #pragma unroll
          for (int nt = 0; nt < 2; ++nt)
            aD[nt] = __builtin_amdgcn_mfma_f32_16x16x32_bf16(
                xf[ks], bg[nt], aD[nt], 0, 0, 0);
        } else {
          #pragma unroll
          for (int nt = 0; nt < 2; ++nt)
            aC[nt] = __builtin_amdgcn_mfma_f32_16x16x32_bf16(
                xf[ks], bg[nt], aC[nt], 0, 0, 0);
        }
      }

      {
        const size_t rowb = (size_t)r0 + kb * 4;
        #pragma unroll
        for (int nt = 0; nt < 2; ++nt) {
          #pragma unroll
          for (int r = 0; r < 4; ++r) {
            const float g = gate[r];
            const float o = fmaf(g, aD[nt][r] - aC[nt][r], aC[nt][r]);
            out[(rowb + r) * CF + (q * 2 + nt) * 16 + cidx] = o;
          }
        }
      }
    }
  }
}

}  // namespace

extern "C" void kernel_launch(void* const* d_in, const int* in_sizes, int n_in,
                              void* d_out, int out_size, void* d_ws, size_t ws_size,
                              hipStream_t stream) {
  const float* xd  = (const float*)d_in[0];
  const float* xc  = (const float*)d_in[1];
  const float* Wd  = (const float*)d_in[2];
  const float* Wc  = (const float*)d_in[3];
  const float* Wg1 = (const float*)d_in[4];
  const float* gma = (const float*)d_in[5];
  const float* bta = (const float*)d_in[6];
  const float* Wg2 = (const float*)d_in[7];
  float* out = (float*)d_out;
  short* ws  = (short*)d_ws;   // needs 60 KB

  const int N = in_sizes[0] / CD;
  const int nTiles = N / 16;             // N % 16 == 0 -> 31250

  convert_weights<<<dim3(15), dim3(256), 0, stream>>>(Wd, Wc, Wg1, ws);

  const int nblk   = 512;                // persistent: 2 blocks/CU
  const int nWaves = nblk * 8;           // 4096 waves
  const int T      = (nTiles + nWaves - 1) / nWaves;   // 8 tiles/wave
  gate_fusion_mfma<<<dim3(nblk), dim3(512), 0, stream>>>(
      xd, xc, gma, bta, Wg2, ws, out, nTiles, T);
}

// Round 17
// 131.550 us; speedup vs baseline: 1.2171x; 1.2171x over previous
//
#include <hip/hip_runtime.h>
#include <hip/hip_bf16.h>
#include <math.h>

// GateFusion via bf16 MFMA (16x16x32). ASM-PIPELINED 4-tile wave: double
// register sets A/B filled by immovable inline-asm load bursts; counted
// s_waitcnt vmcnt(10) (carrying the buffer regs as "+v") lets tile t+1's
// loads stay in flight across tile t's whole compute. This attacks the one
// surviving theory for the occupancy/flight-depth/coalescing-invariant
// 2.8 TB/s wall (r5..r16): per-wave memory duty cycle ~45% (burst->drain->
// compute with memory idle). All 60KB of weights staged in LDS so the
// compute phase issues no global loads (clean vmcnt accounting: 10 burst
// loads + 32 stores per tile; vmcnt(10) after issuing the next burst
// guarantees the previous set + older stores retired).
// out = g * (x_d@W_d) + (1-g) * (x_c@W_c),
// g = sigmoid( relu(LN(concat@Wg1)) @ Wg2 ),  per row.
//
// d_ws: fragment-linear bf16 weights; lane l of frag holds B[k(l,j)][n],
//   n = nt*16 + (l&15),  k(l,j) = ks*32 + (j>>2)*16 + (l>>4)*4 + (j&3)
// (coalesced-load k-permutation; cancels between A and B fragments).

namespace {

typedef __attribute__((ext_vector_type(8))) short short8;
typedef __attribute__((ext_vector_type(4))) float f32x4;

constexpr int CD = 64, CC = 96, CH = 64, CF = 128;
constexpr int NFG1 = 20;   // gate-weight frags
constexpr int NFCB = 40;   // output-weight frags
constexpr int NFRAG = NFG1 + NFCB;            // 60 frags = 61440 B in LDS
constexpr int WCH_ALL = NFRAG * 512 * 2 / 16; // 3840 x 16B

__device__ inline short bf16_of(float f) {
  __hip_bfloat16 h = __float2bfloat16(f);
  return *reinterpret_cast<short*>(&h);
}

__global__ void convert_weights(const float* __restrict__ Wd,
                                const float* __restrict__ Wc,
                                const float* __restrict__ Wg1,
                                short* __restrict__ ws) {
  const int t = blockIdx.x * 256 + threadIdx.x;
  if (t >= 64 * NFRAG) return;
  const int frag = t >> 6, l = t & 63;
  const int cidx = l & 15, kb = l >> 4;
  float v[8];
  if (frag < NFG1) {
    const int ks = frag >> 2, nt = frag & 3;
    const int n = nt * 16 + cidx;
    #pragma unroll
    for (int j = 0; j < 8; ++j) {
      const int k = ks * 32 + (j >> 2) * 16 + kb * 4 + (j & 3);
      v[j] = Wg1[k * CH + n];
    }
  } else {
    const int f2 = frag - NFG1;
    const int ks = f2 >> 3, nt = f2 & 7;
    const int n = nt * 16 + cidx;
    #pragma unroll
    for (int j = 0; j < 8; ++j) {
      const int k = ks * 32 + (j >> 2) * 16 + kb * 4 + (j & 3);
      v[j] = (k < CD) ? Wd[k * CF + n] : Wc[(k - CD) * CF + n];
    }
  }
  short8 o;
  #pragma unroll
  for (int j = 0; j < 8; ++j) o[j] = bf16_of(v[j]);
  *reinterpret_cast<short8*>(ws + frag * 512 + l * 8) = o;
}

// 10 global_load_dwordx4 as one immovable block (4 x_d + 6 x_c segments).
#define BURST(p0,p1,p2,p3,p4,p5,p6,p7,p8,p9, rdp, rcp)                 \
  asm volatile(                                                        \
      "global_load_dwordx4 %0, %[ad], off\n\t"                         \
      "global_load_dwordx4 %1, %[ad], off offset:64\n\t"               \
      "global_load_dwordx4 %2, %[ad], off offset:128\n\t"              \
      "global_load_dwordx4 %3, %[ad], off offset:192\n\t"              \
      "global_load_dwordx4 %4, %[ac], off\n\t"                         \
      "global_load_dwordx4 %5, %[ac], off offset:64\n\t"               \
      "global_load_dwordx4 %6, %[ac], off offset:128\n\t"              \
      "global_load_dwordx4 %7, %[ac], off offset:192\n\t"              \
      "global_load_dwordx4 %8, %[ac], off offset:256\n\t"              \
      "global_load_dwordx4 %9, %[ac], off offset:320"                  \
      : "=&v"(p0), "=&v"(p1), "=&v"(p2), "=&v"(p3), "=&v"(p4),         \
        "=&v"(p5), "=&v"(p6), "=&v"(p7), "=&v"(p8), "=&v"(p9)          \
      : [ad] "v"(rdp), [ac] "v"(rcp)                                   \
      : "memory")

// Wait until <=N VMEM ops outstanding; carries the buffer regs so every
// consumer is data-dependent on the wait (cannot be hoisted above it).
#define WAITB(N, p0,p1,p2,p3,p4,p5,p6,p7,p8,p9)                        \
  asm volatile("s_waitcnt vmcnt(" #N ")"                               \
      : "+v"(p0), "+v"(p1), "+v"(p2), "+v"(p3), "+v"(p4),              \
        "+v"(p5), "+v"(p6), "+v"(p7), "+v"(p8), "+v"(p9)               \
      :: "memory")

__global__ __launch_bounds__(512)
void gate_fusion_mfma(const float* __restrict__ xd,
                      const float* __restrict__ xc,
                      const float* __restrict__ gma,
                      const float* __restrict__ bta,
                      const float* __restrict__ Wg2,
                      const short* __restrict__ wf,
                      float* __restrict__ out, int nTiles) {
  __shared__ short wlds[NFRAG * 512];

  const int tid  = threadIdx.x;
  const int lane = tid & 63;
  const int wv   = tid >> 6;                 // 0..7
  const int cidx = lane & 15;
  const int kb   = lane >> 4;
  const int tb   = (blockIdx.x * 8 + wv) * 4;   // 4 contiguous tiles per wave

  // ---- stage all 60 weight frags (61440 B) into LDS
  for (int c = tid; c < WCH_ALL; c += 512) {
    short8 v = *reinterpret_cast<const short8*>(wf + (size_t)c * 8);
    *reinterpret_cast<short8*>(&wlds[c * 8]) = v;
  }
  __syncthreads();   // the only barrier

  // per-wave constants (cache-hit; complete before first counted wait)
  float gmv[4], btv[4], w2v[4];
  #pragma unroll
  for (int nt = 0; nt < 4; ++nt) {
    const int c = nt * 16 + cidx;
    gmv[nt] = gma[c]; btv[nt] = bta[c]; w2v[nt] = Wg2[c];
  }

  const f32x4 vzero = {0.f, 0.f, 0.f, 0.f};

  auto addrD = [&](int t) {
    const int tc = (t < nTiles) ? t : (nTiles - 1);
    return xd + ((size_t)tc * 16 + cidx) * CD + kb * 4;
  };
  auto addrC = [&](int t) {
    const int tc = (t < nTiles) ? t : (nTiles - 1);
    return xc + ((size_t)tc * 16 + cidx) * CC + kb * 4;
  };

  // compute one 16-row tile from a register set (LDS weights only)
  auto compute = [&](int t, const f32x4& l0, const f32x4& h0,
                     const f32x4& l1, const f32x4& h1,
                     const f32x4& l2, const f32x4& h2,
                     const f32x4& l3, const f32x4& h3,
                     const f32x4& l4, const f32x4& h4) {
    const int r0 = t * 16;
    const f32x4 lo[5] = {l0, l1, l2, l3, l4};
    const f32x4 hi[5] = {h0, h1, h2, h3, h4};
    short8 xf[5];
    #pragma unroll
    for (int ks = 0; ks < 5; ++ks) {
      short8 f;
      #pragma unroll
      for (int j = 0; j < 4; ++j) {
        f[j]     = bf16_of(lo[ks][j]);
        f[4 + j] = bf16_of(hi[ks][j]);
      }
      xf[ks] = f;
    }

    // phase 1: h = x @ Wg1 (B-frags from LDS)
    f32x4 acc1[4];
    #pragma unroll
    for (int nt = 0; nt < 4; ++nt) acc1[nt] = vzero;
    #pragma unroll
    for (int ks = 0; ks < 5; ++ks) {
      short8 bg[4];
      #pragma unroll
      for (int nt = 0; nt < 4; ++nt)
        bg[nt] = *reinterpret_cast<const short8*>(
            &wlds[(ks * 4 + nt) * 512 + lane * 8]);
      #pragma unroll
      for (int nt = 0; nt < 4; ++nt)
        acc1[nt] = __builtin_amdgcn_mfma_f32_16x16x32_bf16(
            xf[ks], bg[nt], acc1[nt], 0, 0, 0);
    }

    // LayerNorm + relu + dot(Wg2) + sigmoid
    float gate[4];
    {
      float s[4], q[4];
      #pragma unroll
      for (int r = 0; r < 4; ++r) {
        s[r] = 0.f; q[r] = 0.f;
        #pragma unroll
        for (int nt = 0; nt < 4; ++nt) {
          const float c = acc1[nt][r];
          s[r] += c; q[r] += c * c;
        }
      }
      #pragma unroll
      for (int m = 1; m < 16; m <<= 1)
        #pragma unroll
        for (int r = 0; r < 4; ++r) {
          s[r] += __shfl_xor(s[r], m, 64);
          q[r] += __shfl_xor(q[r], m, 64);
        }
      float p[4];
      #pragma unroll
      for (int r = 0; r < 4; ++r) {
        const float mu  = s[r] * (1.f / CH);
        const float var = q[r] * (1.f / CH) - mu * mu;
        const float rsd = rsqrtf(var + 1e-5f);
        float pp = 0.f;
        #pragma unroll
        for (int nt = 0; nt < 4; ++nt) {
          const float h = fmaxf((acc1[nt][r] - mu) * rsd * gmv[nt] + btv[nt], 0.f);
          pp += h * w2v[nt];
        }
        p[r] = pp;
      }
      #pragma unroll
      for (int m = 1; m < 16; m <<= 1)
        #pragma unroll
        for (int r = 0; r < 4; ++r) p[r] += __shfl_xor(p[r], m, 64);
      #pragma unroll
      for (int r = 0; r < 4; ++r) gate[r] = 1.f / (1.f + expf(-p[r]));
    }

    // phase 2 in 4 nt-quarter slices (LDS weights), blend, store
    #pragma unroll
    for (int q = 0; q < 4; ++q) {
      f32x4 aD[2], aC[2];
      #pragma unroll
      for (int nt = 0; nt < 2; ++nt) { aD[nt] = vzero; aC[nt] = vzero; }
      #pragma unroll
      for (int ks = 0; ks < 5; ++ks) {
        short8 bg[2];
        #pragma unroll
        for (int nt = 0; nt < 2; ++nt)
          bg[nt] = *reinterpret_cast<const short8*>(
              &wlds[(NFG1 + ks * 8 + q * 2 + nt) * 512 + lane * 8]);
        if (ks < 2) {
          #pragma unroll
          for (int nt = 0; nt < 2; ++nt)
            aD[nt] = __builtin_amdgcn_mfma_f32_16x16x32_bf16(
                xf[ks], bg[nt], aD[nt], 0, 0, 0);
        } else {
          #pragma unroll
          for (int nt = 0; nt < 2; ++nt)
            aC[nt] = __builtin_amdgcn_mfma_f32_16x16x32_bf16(
                xf[ks], bg[nt], aC[nt], 0, 0, 0);
        }
      }
      const size_t rowb = (size_t)r0 + kb * 4;
      #pragma unroll
      for (int nt = 0; nt < 2; ++nt) {
        #pragma unroll
        for (int r = 0; r < 4; ++r) {
          const float g = gate[r];
          const float o = fmaf(g, aD[nt][r] - aC[nt][r], aC[nt][r]);
          out[(rowb + r) * CF + (q * 2 + nt) * 16 + cidx] = o;
        }
      }
    }
  };

  // ---- 4-tile software pipeline, straight-line
  f32x4 a0, a1, a2, a3, a4, a5, a6, a7, a8, a9;
  f32x4 b0, b1, b2, b3, b4, b5, b6, b7, b8, b9;

  BURST(a0,a1,a2,a3,a4,a5,a6,a7,a8,a9, addrD(tb),     addrC(tb));
  BURST(b0,b1,b2,b3,b4,b5,b6,b7,b8,b9, addrD(tb + 1), addrC(tb + 1));

  WAITB(10, a0,a1,a2,a3,a4,a5,a6,a7,a8,a9);
  if (tb < nTiles)     compute(tb,     a0,a1, a2,a3, a4,a5, a6,a7, a8,a9);

  BURST(a0,a1,a2,a3,a4,a5,a6,a7,a8,a9, addrD(tb + 2), addrC(tb + 2));
  WAITB(10, b0,b1,b2,b3,b4,b5,b6,b7,b8,b9);
  if (tb + 1 < nTiles) compute(tb + 1, b0,b1, b2,b3, b4,b5, b6,b7, b8,b9);

  BURST(b0,b1,b2,b3,b4,b5,b6,b7,b8,b9, addrD(tb + 3), addrC(tb + 3));
  WAITB(10, a0,a1,a2,a3,a4,a5,a6,a7,a8,a9);
  if (tb + 2 < nTiles) compute(tb + 2, a0,a1, a2,a3, a4,a5, a6,a7, a8,a9);

  WAITB(0, b0,b1,b2,b3,b4,b5,b6,b7,b8,b9);
  if (tb + 3 < nTiles) compute(tb + 3, b0,b1, b2,b3, b4,b5, b6,b7, b8,b9);
}

}  // namespace

extern "C" void kernel_launch(void* const* d_in, const int* in_sizes, int n_in,
                              void* d_out, int out_size, void* d_ws, size_t ws_size,
                              hipStream_t stream) {
  const float* xd  = (const float*)d_in[0];
  const float* xc  = (const float*)d_in[1];
  const float* Wd  = (const float*)d_in[2];
  const float* Wc  = (const float*)d_in[3];
  const float* Wg1 = (const float*)d_in[4];
  const float* gma = (const float*)d_in[5];
  const float* bta = (const float*)d_in[6];
  const float* Wg2 = (const float*)d_in[7];
  float* out = (float*)d_out;
  short* ws  = (short*)d_ws;   // needs 60 KB

  const int N = in_sizes[0] / CD;
  const int nTiles = N / 16;             // 31250

  convert_weights<<<dim3(15), dim3(256), 0, stream>>>(Wd, Wc, Wg1, ws);

  const int tilesPerBlock = 8 * 4;       // 8 waves x 4 tiles
  const int nblk = (nTiles + tilesPerBlock - 1) / tilesPerBlock;
  gate_fusion_mfma<<<dim3(nblk), dim3(512), 0, stream>>>(
      xd, xc, gma, bta, Wg2, ws, out, nTiles);
}

// Round 18
// 126.835 us; speedup vs baseline: 1.2624x; 1.0372x over previous
//
#include <hip/hip_runtime.h>
#include <hip/hip_bf16.h>
#include <math.h>

// GateFusion via bf16 MFMA (16x16x32). r14 one-shot body + TRANSPOSED
// NONTEMPORAL EPILOGUE: phase-2 results for all 4 q-slices stay in registers,
// a per-wave LDS bounce (4x132 f32 scratch) converts the MFMA column-fragment
// layout to row-contiguous form, and output is written with 8
// global_store_dwordx4 nt per tile (1KB/inst, 512B-contiguous row segments)
// instead of 32 scalar dword stores. Rationale: 8 rounds of invariance
// (occupancy/flight-depth/coalescing/pipelining all falsified) leave the
// L2/L3 write-allocate path as the surviving ~4.4 TB/s choke; NT+wide streams
// writes past L3 without RMW (r3's NT failure was 4B/lane fragments) and
// frees L3 for the read stream.
// out = g * (x_d@W_d) + (1-g) * (x_c@W_c),
// g = sigmoid( relu(LN(concat@Wg1)) @ Wg2 ),  per row.
//
// d_ws: fragment-linear bf16 weights; lane l of frag holds B[k(l,j)][n],
//   n = nt*16 + (l&15),  k(l,j) = ks*32 + (j>>2)*16 + (l>>4)*4 + (j&3)
// (coalesced-load k-permutation; cancels between A and B fragments).

namespace {

typedef __attribute__((ext_vector_type(8))) short short8;
typedef __attribute__((ext_vector_type(4))) float f32x4;

constexpr int CD = 64, CC = 96, CH = 64, CF = 128;
constexpr int NFG1 = 20;   // gate-weight frags (read from L1/L2)
constexpr int NFCB = 40;   // output-weight frags (staged in LDS)
constexpr int NFRAG = NFG1 + NFCB;
constexpr int WCHUNKS = NFCB * 512 * 2 / 16;  // 2560 x 16B = 40960 B

__device__ inline short bf16_of(float f) {
  __hip_bfloat16 h = __float2bfloat16(f);
  return *reinterpret_cast<short*>(&h);
}

__global__ void convert_weights(const float* __restrict__ Wd,
                                const float* __restrict__ Wc,
                                const float* __restrict__ Wg1,
                                short* __restrict__ ws) {
  const int t = blockIdx.x * 256 + threadIdx.x;
  if (t >= 64 * NFRAG) return;
  const int frag = t >> 6, l = t & 63;
  const int cidx = l & 15, kb = l >> 4;
  float v[8];
  if (frag < NFG1) {
    const int ks = frag >> 2, nt = frag & 3;
    const int n = nt * 16 + cidx;
    #pragma unroll
    for (int j = 0; j < 8; ++j) {
      const int k = ks * 32 + (j >> 2) * 16 + kb * 4 + (j & 3);
      v[j] = Wg1[k * CH + n];
    }
  } else {
    const int f2 = frag - NFG1;
    const int ks = f2 >> 3, nt = f2 & 7;
    const int n = nt * 16 + cidx;
    #pragma unroll
    for (int j = 0; j < 8; ++j) {
      const int k = ks * 32 + (j >> 2) * 16 + kb * 4 + (j & 3);
      v[j] = (k < CD) ? Wd[k * CF + n] : Wc[(k - CD) * CF + n];
    }
  }
  short8 o;
  #pragma unroll
  for (int j = 0; j < 8; ++j) o[j] = bf16_of(v[j]);
  *reinterpret_cast<short8*>(ws + frag * 512 + l * 8) = o;
}

__global__ __launch_bounds__(512, 4)
void gate_fusion_mfma(const float* __restrict__ xd,
                      const float* __restrict__ xc,
                      const float* __restrict__ gma,
                      const float* __restrict__ bta,
                      const float* __restrict__ Wg2,
                      const short* __restrict__ wf,
                      float* __restrict__ out, int N) {
  __shared__ short wlds[NFCB * 512];     // 40960 B
  __shared__ float tr[8][4][132];        // 16896 B: per-wave transpose scratch

  const int tid  = threadIdx.x;
  const int lane = tid & 63;
  const int wv   = tid >> 6;                 // 0..7
  const int r0   = blockIdx.x * 128 + wv * 16;   // 16 rows per wave
  const int cidx = lane & 15;
  const int kb   = lane >> 4;
  const bool active = (r0 < N);              // wave-uniform (N % 16 == 0)

  // ---- x loads (coalesced 64B/4-lane segments, r14 k-map)
  f32x4 buf[5][2];
  if (active) {
    const size_t row = (size_t)(r0 + cidx);
    const float* rd = xd + row * CD + kb * 4;
    const float* rc = xc + row * CC + kb * 4;
    #pragma unroll
    for (int ks = 0; ks < 5; ++ks) {
      const float* p = (ks < 2) ? (rd + ks * 32) : (rc + (ks - 2) * 32);
      buf[ks][0] = *reinterpret_cast<const f32x4*>(p);
      buf[ks][1] = *reinterpret_cast<const f32x4*>(p + 16);
    }
  }

  // ---- stage the 40 output-weight frags (40960 B) into LDS
  {
    const short* wsrc = wf + NFG1 * 512;
    #pragma unroll
    for (int it = 0; it < WCHUNKS / 512; ++it) {
      const int c = tid + it * 512;
      short8 v = *reinterpret_cast<const short8*>(wsrc + (size_t)c * 8);
      *reinterpret_cast<short8*>(&wlds[c * 8]) = v;
    }
  }

  __syncthreads();
  if (!active) return;   // after the only barrier

  // per-wave constants (cache-hit loads)
  float gmv[4], btv[4], w2v[4];
  #pragma unroll
  for (int nt = 0; nt < 4; ++nt) {
    const int c = nt * 16 + cidx;
    gmv[nt] = gma[c]; btv[nt] = bta[c]; w2v[nt] = Wg2[c];
  }

  // ---- convert x to bf16 A-fragments
  short8 xf[5];
  #pragma unroll
  for (int ks = 0; ks < 5; ++ks) {
    short8 f;
    #pragma unroll
    for (int j = 0; j < 4; ++j) {
      f[j]     = bf16_of(buf[ks][0][j]);
      f[4 + j] = bf16_of(buf[ks][1][j]);
    }
    xf[ks] = f;
  }

  // ---- phase 1: h = x @ Wg1  [16 x 64]  (B-frags from L1/L2)
  const f32x4 vzero = {0.f, 0.f, 0.f, 0.f};
  f32x4 acc1[4];
  #pragma unroll
  for (int nt = 0; nt < 4; ++nt) acc1[nt] = vzero;

  #pragma unroll
  for (int ks = 0; ks < 5; ++ks) {
    short8 bg[4];
    #pragma unroll
    for (int nt = 0; nt < 4; ++nt)
      bg[nt] = *reinterpret_cast<const short8*>(wf + (ks * 4 + nt) * 512 + lane * 8);
    #pragma unroll
    for (int nt = 0; nt < 4; ++nt)
      acc1[nt] = __builtin_amdgcn_mfma_f32_16x16x32_bf16(
          xf[ks], bg[nt], acc1[nt], 0, 0, 0);
  }

  // ---- LayerNorm + relu + dot(Wg2) + sigmoid (C-fragment layout)
  float gate[4];
  {
    float s[4], q[4];
    #pragma unroll
    for (int r = 0; r < 4; ++r) {
      s[r] = 0.f; q[r] = 0.f;
      #pragma unroll
      for (int nt = 0; nt < 4; ++nt) {
        const float c = acc1[nt][r];
        s[r] += c; q[r] += c * c;
      }
    }
    #pragma unroll
    for (int m = 1; m < 16; m <<= 1)
      #pragma unroll
      for (int r = 0; r < 4; ++r) {
        s[r] += __shfl_xor(s[r], m, 64);
        q[r] += __shfl_xor(q[r], m, 64);
      }
    float p[4];
    #pragma unroll
    for (int r = 0; r < 4; ++r) {
      const float mu  = s[r] * (1.f / CH);
      const float var = q[r] * (1.f / CH) - mu * mu;
      const float rsd = rsqrtf(var + 1e-5f);
      float pp = 0.f;
      #pragma unroll
      for (int nt = 0; nt < 4; ++nt) {
        const float h = fmaxf((acc1[nt][r] - mu) * rsd * gmv[nt] + btv[nt], 0.f);
        pp += h * w2v[nt];
      }
      p[r] = pp;
    }
    #pragma unroll
    for (int m = 1; m < 16; m <<= 1)
      #pragma unroll
      for (int r = 0; r < 4; ++r) p[r] += __shfl_xor(p[r], m, 64);
    #pragma unroll
    for (int r = 0; r < 4; ++r) gate[r] = 1.f / (1.f + expf(-p[r]));
  }

  // ---- phase 2: all 4 nt-quarter slices, blended results kept in registers
  f32x4 o[4][2];
  #pragma unroll
  for (int q = 0; q < 4; ++q) {
    f32x4 aD[2], aC[2];
    #pragma unroll
    for (int nt = 0; nt < 2; ++nt) { aD[nt] = vzero; aC[nt] = vzero; }

    #pragma unroll
    for (int ks = 0; ks < 5; ++ks) {
      short8 bg[2];
      #pragma unroll
      for (int nt = 0; nt < 2; ++nt)
        bg[nt] = *reinterpret_cast<const short8*>(
            &wlds[(ks * 8 + q * 2 + nt) * 512 + lane * 8]);
      if (ks < 2) {
        #pragma unroll
        for (int nt = 0; nt < 2; ++nt)
          aD[nt] = __builtin_amdgcn_mfma_f32_16x16x32_bf16(
              xf[ks], bg[nt], aD[nt], 0, 0, 0);
      } else {
        #pragma unroll
        for (int nt = 0; nt < 2; ++nt)
          aC[nt] = __builtin_amdgcn_mfma_f32_16x16x32_bf16(
              xf[ks], bg[nt], aC[nt], 0, 0, 0);
      }
    }
    #pragma unroll
    for (int nt = 0; nt < 2; ++nt)
      #pragma unroll
      for (int r = 0; r < 4; ++r)
        o[q][nt][r] = fmaf(gate[r], aD[nt][r] - aC[nt][r], aC[nt][r]);
  }

  // ---- transpose via per-wave LDS scratch + wide NT stores.
  // Fragment layout: o[q][nt][r] is row kb*4+r, col (q*2+nt)*16+cidx.
  // For each r: scratch[kb][col] <- o[..][..][r]; then 2 insts store
  // rows {r0+0*4+r .. r0+3*4+r} as 512B-contiguous dwordx4 nt.
  {
    float (*trw)[132] = tr[wv];
    #pragma unroll
    for (int r = 0; r < 4; ++r) {
      #pragma unroll
      for (int q = 0; q < 4; ++q)
        #pragma unroll
        for (int nt = 0; nt < 2; ++nt)
          trw[kb][(q * 2 + nt) * 16 + cidx] = o[q][nt][r];
      // same-wave LDS write->read: in-order DS pipe + compiler lgkmcnt
      #pragma unroll
      for (int i = 0; i < 2; ++i) {
        const int ri = i * 2 + (lane >> 5);          // scratch row 0..3
        const f32x4 v = *reinterpret_cast<const f32x4*>(
            &trw[ri][(lane & 31) * 4]);
        float* dst = &out[((size_t)r0 + ri * 4 + r) * CF + (lane & 31) * 4];
        asm volatile("global_store_dwordx4 %0, %1, off nt"
                     :: "v"(dst), "v"(v) : "memory");
      }
    }
  }
}

}  // namespace

extern "C" void kernel_launch(void* const* d_in, const int* in_sizes, int n_in,
                              void* d_out, int out_size, void* d_ws, size_t ws_size,
                              hipStream_t stream) {
  const float* xd  = (const float*)d_in[0];
  const float* xc  = (const float*)d_in[1];
  const float* Wd  = (const float*)d_in[2];
  const float* Wc  = (const float*)d_in[3];
  const float* Wg1 = (const float*)d_in[4];
  const float* gma = (const float*)d_in[5];
  const float* bta = (const float*)d_in[6];
  const float* Wg2 = (const float*)d_in[7];
  float* out = (float*)d_out;
  short* ws  = (short*)d_ws;   // needs 60 KB

  const int N = in_sizes[0] / CD;

  convert_weights<<<dim3(15), dim3(256), 0, stream>>>(Wd, Wc, Wg1, ws);

  const int nblk = (N + 127) / 128;   // 128 rows per 8-wave block
  gate_fusion_mfma<<<dim3(nblk), dim3(512), 0, stream>>>(
      xd, xc, gma, bta, Wg2, ws, out, N);
}